// Round 8
// baseline (224.336 us; speedup 1.0000x reference)
//
#include <hip/hip_runtime.h>
#include <hip/hip_bf16.h>

// GCN layer: out = relu( (D^-1/2 A D^-1/2) @ (x @ W) ) over channel dim.
// B=16, C=64, S=2048, Fin=Fout=64.
#define B_ 16
#define C_ 64
#define S_ 2048
#define F_ 64
#define SF (S_ * F_)   // 131072, stride between channels

typedef __attribute__((ext_vector_type(8))) short short8;   // 8 bf16 (4 VGPRs) MFMA A/B frag
typedef __attribute__((ext_vector_type(4))) float float4_;  // MFMA C/D frag

// bf16-tile XOR-swizzle (halfword units, 16B granules)
#define SWZ(row, col) ((col) ^ (((row) & 7) << 3))
// fp32-tile XOR-swizzle (dword units, 16B granules)
#define SWZ4(row, col) ((col) ^ (((row) & 7) << 2))

__device__ __forceinline__ unsigned short f2bf(float f) {
    // RNE fp32->bf16 via integer ops (proven numerics)
    unsigned int u = __builtin_bit_cast(unsigned int, f);
    u += 0x7fffu + ((u >> 16) & 1u);
    return (unsigned short)(u >> 16);
}

// ---------------------------------------------------------------------------
// Prep: norm_adj -> bf16 [c][d];  wT[o][f] = bf16(weight[f][o]).
// Rowsum via 4-thread split + shuffles (round-2 proven).
// ---------------------------------------------------------------------------
__global__ void gcn_prep(const float* __restrict__ adj, const float* __restrict__ wgt,
                         unsigned short* __restrict__ nadj, unsigned short* __restrict__ wT)
{
    __shared__ float dis[C_];
    const int t = threadIdx.x;          // 256 threads
    {
        const int r = t >> 2, q = t & 3;
        float p = 0.f;
        const float* ar = adj + r * C_ + q * 16;
#pragma unroll
        for (int j = 0; j < 16; ++j) p += ar[j];
        p += __shfl_xor(p, 1);
        p += __shfl_xor(p, 2);
        if (q == 0) dis[r] = rsqrtf(p);
    }
    __syncthreads();
    for (int i = t; i < C_ * C_; i += 256) {
        const int c = i >> 6, d = i & 63;
        nadj[i] = f2bf(adj[i] * dis[c] * dis[d]);
        wT[d * F_ + c] = f2bf(wgt[i]);   // wgt[f=c][o=d] -> wT[o][f]
    }
}

// ---------------------------------------------------------------------------
// Main: one block = (b, 8 consecutive s); one wave = one s. After the table
// fill there are NO block barriers: each wave stages through its private 4KB
// LDS tile; stores are full-line, CACHED (L2 write aggregation).
// Stage 1: sup[d][o] = x[b,d,s,:] @ W ; per-ot wave-local transpose -> aA regs.
// Stage 2: per ct (16 c-rows): mfma(aA, nadj) -> relu -> swizzled LDS tile ->
//          read back as 4 store-instrs, each 4 x 256B contiguous runs.
// ---------------------------------------------------------------------------
__global__ __launch_bounds__(512, 4) void gcn_main(
    const float* __restrict__ x,
    const unsigned short* __restrict__ nadj,
    const unsigned short* __restrict__ wT,
    float* __restrict__ out)
{
    __shared__ __align__(16) unsigned short lds_nadj[C_ * C_];   // 8 KB, swizzled
    __shared__ __align__(16) unsigned short lds_wT[F_ * F_];     // 8 KB, swizzled
    __shared__ __align__(16) float obuf_all[8][16 * 64];         // 4 KB per wave (unions supT)

    const int tid  = threadIdx.x;
    const int w    = tid >> 6;          // wave id 0..7  == s within tile
    const int l    = tid & 63;
    const int lrow = l & 15;
    const int lgrp = l >> 4;            // 0..3

    // ---- cooperative fill of nadj/wT into swizzled LDS (16B per thread each)
    {
        const int fc = tid >> 3;          // row 0..63
        const int fd = (tid & 7) * 8;     // col base
        *(short8*)(lds_nadj + fc * 64 + SWZ(fc, fd)) = *(const short8*)(nadj + fc * 64 + fd);
        *(short8*)(lds_wT  + fc * 64 + SWZ(fc, fd)) = *(const short8*)(wT  + fc * 64 + fd);
    }
    __syncthreads();    // the only block barrier

    const int b  = blockIdx.x >> 8;     // 256 s-tiles per b
    const int st = blockIdx.x & 255;
    const int s  = st * 8 + w;

    // ---- load x A-fragments for all 64 channels (nontemporal; fp32 -> bf16)
    const float* xb = x + (size_t)b * C_ * SF + (size_t)s * F_;
    short8 af[4][2];
#pragma unroll
    for (int dt = 0; dt < 4; ++dt) {
        const float* xr = xb + (size_t)(dt * 16 + lrow) * SF;
#pragma unroll
        for (int ks = 0; ks < 2; ++ks) {
            float4_ u0 = __builtin_nontemporal_load((const float4_*)(xr + ks * 32 + lgrp * 8));
            float4_ u1 = __builtin_nontemporal_load((const float4_*)(xr + ks * 32 + lgrp * 8 + 4));
            short8 a;
#pragma unroll
            for (int j = 0; j < 4; ++j) {
                a[j]     = (short)f2bf(u0[j]);
                a[4 + j] = (short)f2bf(u1[j]);
            }
            af[dt][ks] = a;
        }
    }

    float* myO = obuf_all[w];                       // fp32 [16][64] view (stage 2)
    unsigned short* myT = (unsigned short*)myO;     // bf16 [16][64] view (stage 1, first 2KB)

    // ---- Stage 1: per o-tile, sup[d][o] -> wave-local transpose -> aA regs
    short8 aA[4][2];
#pragma unroll
    for (int ot = 0; ot < 4; ++ot) {
        const int orow = ot * 16 + lrow;
        short8 wf0 = *(const short8*)(lds_wT + orow * 64 + SWZ(lrow, lgrp * 8));
        short8 wf1 = *(const short8*)(lds_wT + orow * 64 + SWZ(lrow, 32 + lgrp * 8));
#pragma unroll
        for (int dt = 0; dt < 4; ++dt) {
            float4_ s1 = {0.f, 0.f, 0.f, 0.f};
            s1 = __builtin_amdgcn_mfma_f32_16x16x32_bf16(af[dt][0], wf0, s1, 0, 0, 0);
            s1 = __builtin_amdgcn_mfma_f32_16x16x32_bf16(af[dt][1], wf1, s1, 0, 0, 0);
            const int dbase = dt * 16 + lgrp * 4;     // C-frag rows = d
            uint2 pk;                                  // lane's col = o = orow
            pk.x = (unsigned)f2bf(s1[0]) | ((unsigned)f2bf(s1[1]) << 16);
            pk.y = (unsigned)f2bf(s1[2]) | ((unsigned)f2bf(s1[3]) << 16);
            *(uint2*)(myT + lrow * 64 + SWZ(lrow, dbase)) = pk;
        }
        // sup^T fragments (A-operand, stage 2): row = o_local = lrow, k = d
        aA[ot][0] = *(const short8*)(myT + lrow * 64 + SWZ(lrow, lgrp * 8));
        aA[ot][1] = *(const short8*)(myT + lrow * 64 + SWZ(lrow, 32 + lgrp * 8));
    }
    // (myT region dead once aA loaded; within-wave lgkmcnt ordering protects reuse)

    // ---- Stage 2: per c-tile: MFMA -> relu -> private LDS tile -> full-line stores
#pragma unroll 1
    for (int ct = 0; ct < 4; ++ct) {
        const int crow = ct * 16 + lrow;
        short8 an0 = *(const short8*)(lds_nadj + crow * 64 + SWZ(lrow, lgrp * 8));
        short8 an1 = *(const short8*)(lds_nadj + crow * 64 + SWZ(lrow, 32 + lgrp * 8));

#pragma unroll
        for (int ot = 0; ot < 4; ++ot) {
            float4_ acc = {0.f, 0.f, 0.f, 0.f};
            acc = __builtin_amdgcn_mfma_f32_16x16x32_bf16(aA[ot][0], an0, acc, 0, 0, 0);
            acc = __builtin_amdgcn_mfma_f32_16x16x32_bf16(aA[ot][1], an1, acc, 0, 0, 0);
            float4_ r;
#pragma unroll
            for (int j = 0; j < 4; ++j) r[j] = fmaxf(acc[j], 0.f);
            // lane holds out[c=crow][o = ot*16 + lgrp*4 + j]; stage in own tile,
            // dword-col swizzled (conflict-free per 8-lane phase)
            *(float4_*)(myO + lrow * 64 + SWZ4(lrow, ot * 16 + lgrp * 4)) = r;
        }

        // read back + store: 4 instrs, each = 4 c-rows x 256B contiguous runs;
        // CACHED stores (full lines) so L2 aggregates writebacks into bursts.
#pragma unroll
        for (int t = 0; t < 4; ++t) {
            const int cl  = t * 4 + (l >> 4);       // c-local 0..15
            const int col = (l & 15) * 4;           // dword col 0..60
            float4_ v = *(const float4_*)(myO + cl * 64 + SWZ4(cl, col));
            float* g = out + ((size_t)(b * C_ + ct * 16 + cl) * S_ + s) * F_ + col;
            *(float4_*)g = v;
        }
    }
}

// ---------------------------------------------------------------------------
extern "C" void kernel_launch(void* const* d_in, const int* in_sizes, int n_in,
                              void* d_out, int out_size, void* d_ws, size_t ws_size,
                              hipStream_t stream) {
    const float* x   = (const float*)d_in[0];
    const float* adj = (const float*)d_in[1];
    const float* wgt = (const float*)d_in[2];
    float* out = (float*)d_out;

    unsigned short* nadj = (unsigned short*)d_ws;      // 4096 bf16
    unsigned short* wT   = nadj + C_ * C_;             // 4096 bf16

    gcn_prep<<<1, 256, 0, stream>>>(adj, wgt, nadj, wT);

    dim3 grid(B_ * (S_ / 8));   // 4096 blocks: (b, s-tile of 8)
    gcn_main<<<grid, 512, 0, stream>>>(x, nadj, wT, out);
}